// Round 10
// baseline (153.184 us; speedup 1.0000x reference)
//
#include <hip/hip_runtime.h>
#include <hip/hip_bf16.h>

typedef __attribute__((ext_vector_type(8))) short bf16x8;
typedef __attribute__((ext_vector_type(4))) float f32x4;

namespace {
constexpr int kC = 256;
constexpr int kN = 2048;
constexpr int kB = 4;
constexpr int kHeads = 7;
constexpr int kOC = kHeads * 64;     // 448
constexpr float kLog2e = 1.44269504f;
}

static __device__ __forceinline__ float bf2f(ushort u) {
    union { unsigned u; float f; } v; v.u = ((unsigned)u) << 16;
    return v.f;
}
// packed f32x2 -> bf16x2 (RNE); lowers to v_cvt_pk_bf16_f32 when available
static __device__ __forceinline__ unsigned pk_bf16(float a, float b) {
    __hip_bfloat162 h = __float22bfloat162_rn(make_float2(a, b));
    union { __hip_bfloat162 h; unsigned u; } v; v.h = h;
    return v.u;
}
static __device__ __forceinline__ ushort4 pack4bf(float a, float b, float c, float d) {
    union { ushort4 s; uint2 u; } v;
    v.u.x = pk_bf16(a, b); v.u.y = pk_bf16(c, d);
    return v.s;
}
static __device__ __forceinline__ float fexp2(float x) {
#if __has_builtin(__builtin_amdgcn_exp2f)
    return __builtin_amdgcn_exp2f(x);
#else
    return exp2f(x);
#endif
}
// async global->LDS DMA, 16 B per lane. lds dest = l + lane*16 (wave-uniform l).
static __device__ __forceinline__ void g2l16(const ushort* g, ushort* l) {
    __builtin_amdgcn_global_load_lds(
        (const __attribute__((address_space(1))) void*)g,
        (__attribute__((address_space(3))) void*)l,
        16, 0, 0);
}

// ---------------- fused prep: weight cast + x transpose (one launch) -------
__global__ __launch_bounds__(256) void prep_kernel(
    const float* __restrict__ x,
    const float* __restrict__ Wq, const float* __restrict__ Wk,
    const float* __restrict__ Wv, const float* __restrict__ Wf,
    ushort* __restrict__ xT,
    ushort* __restrict__ wq, ushort* __restrict__ wk,
    ushort* __restrict__ wv, ushort* __restrict__ wf)
{
    __shared__ float T[64][65];
    const int bid = blockIdx.x;
    const int tid = threadIdx.x;
    if (bid < 512) {
        // ---- transpose+cast: x[b][c][n] fp32 -> xT[b][n][c] bf16 ----
        const int nt = bid & 31, ct = (bid >> 5) & 3, b = bid >> 7;
        const float* xb = x + ((size_t)b * kC + ct * 64) * kN + nt * 64;
#pragma unroll
        for (int p = 0; p < 16; ++p) {
            int idx = p * 256 + tid;
            int cc = idx >> 6, nn = idx & 63;
            T[cc][nn] = xb[(size_t)cc * kN + nn];
        }
        __syncthreads();
        ushort* xTb = xT + ((size_t)b * kN + nt * 64) * kC + ct * 64;
#pragma unroll
        for (int p = 0; p < 4; ++p) {
            int nn = p * 16 + (tid >> 4);
            int c4 = (tid & 15) * 4;
            *(ushort4*)&xTb[(size_t)nn * kC + c4] =
                pack4bf(T[c4 + 0][nn], T[c4 + 1][nn], T[c4 + 2][nn], T[c4 + 3][nn]);
        }
    } else {
        // ---- weight cast fp32 -> bf16 ----
        const int j = bid - 512;            // 0..447
        const int which = j / 112, bx = j % 112;
        const float* src = which == 0 ? Wq : which == 1 ? Wk : which == 2 ? Wv : Wf;
        ushort* dst      = which == 0 ? wq : which == 1 ? wk : which == 2 ? wv : wf;
        int n = (which == 3) ? kC * kOC : kC * kC;
        int i = (bx * 256 + tid) * 4;
        if (i < n) {
            float4 v = *(const float4*)(src + i);
            *(ushort4*)(dst + i) = pack4bf(v.x, v.y, v.z, v.w);
        }
    }
}

// ---------------- QKV projection, 128x128 tile, DMA dbuf 1-barrier ---------
__global__ __launch_bounds__(256, 2) void qkv_kernel(
    const ushort* __restrict__ xT,
    const ushort* __restrict__ Wqb, const ushort* __restrict__ Wkb, const ushort* __restrict__ Wvb,
    const float* __restrict__ sq, const float* __restrict__ bq,
    const float* __restrict__ sk, const float* __restrict__ bk,
    const float* __restrict__ sv, const float* __restrict__ bv,
    ushort* __restrict__ qT, ushort* __restrict__ kT, ushort* __restrict__ vB)
{
    const int nt  = blockIdx.x;          // 16 tiles of 128 n
    const int ot  = blockIdx.y;          // 2 tiles of 128 o
    const int b   = blockIdx.z / 3;
    const int mat = blockIdx.z % 3;
    const ushort* Wb = mat == 0 ? Wqb : mat == 1 ? Wkb : Wvb;
    const float* sm = mat == 0 ? sq : mat == 1 ? sk : sv;
    const float* bm = mat == 0 ? bq : mat == 1 ? bk : bv;

    __shared__ __align__(16) ushort lds[4][128 * 64];   // 64 KB

    const int tid = threadIdx.x;
    const int lane = tid & 63, wav = tid >> 6;
    const int quad = lane >> 4, l16 = lane & 15;

    const ushort* xTb = xT + ((size_t)b * kN + nt * 128) * kC;
    const ushort* Wt  = Wb + (size_t)(ot * 128) * kC;

    f32x4 acc[8][2];
#pragma unroll
    for (int mt = 0; mt < 8; ++mt)
#pragma unroll
        for (int ntt = 0; ntt < 2; ++ntt)
#pragma unroll
            for (int r = 0; r < 4; ++r) acc[mt][ntt][r] = 0.f;

    const int sa   = lane >> 3;           // dest sub-row within 8-row chunk
    const int sblk = (lane & 7) ^ sa;     // source block (swizzle on source)
    auto dmaK = [&](int k0, int buf) {
#pragma unroll
        for (int p = 0; p < 4; ++p) {
            int row = wav * 32 + p * 8 + sa;
            size_t so = (size_t)row * kC + k0 + sblk * 8;
            int dbase = (wav * 32 + p * 8) * 64;
            g2l16(Wt + so,  &lds[buf][dbase]);
            g2l16(xTb + so, &lds[2 + buf][dbase]);
        }
    };

    dmaK(0, 0);
    __syncthreads();

    for (int kt = 0; kt < 4; ++kt) {
        const int cur = kt & 1;
        const bool more = (kt < 3);
        if (more) dmaK((kt + 1) * 64, cur ^ 1);

        const ushort* rowB = (mat < 2) ? lds[cur] : lds[2 + cur];
        const ushort* colB = (mat < 2) ? lds[2 + cur] : lds[cur];
#pragma unroll
        for (int ks = 0; ks < 2; ++ks) {
            bf16x8 bfr[2];
#pragma unroll
            for (int ntt = 0; ntt < 2; ++ntt) {
                int row = wav * 32 + ntt * 16 + l16;
                bfr[ntt] = *(const bf16x8*)&colB[row * 64 + (((ks * 4 + quad) ^ (row & 7)) * 8)];
            }
#pragma unroll
            for (int mt = 0; mt < 8; ++mt) {
                int row = mt * 16 + l16;
                bf16x8 af = *(const bf16x8*)&rowB[row * 64 + (((ks * 4 + quad) ^ (row & 7)) * 8)];
#pragma unroll
                for (int ntt = 0; ntt < 2; ++ntt)
                    acc[mt][ntt] = __builtin_amdgcn_mfma_f32_16x16x32_bf16(
                        af, bfr[ntt], acc[mt][ntt], 0, 0, 0);
            }
        }
        __syncthreads();
    }

    // epilogue: 128x128 transpose gather in lds[0..1] (32 KB, contiguous)
    ushort* sT = &lds[0][0];
    const float qs = (mat == 0) ? kLog2e : 1.f;   // bake log2e into q

    if (mat < 2) {
#pragma unroll
        for (int mt = 0; mt < 8; ++mt) {
            float4 sc4 = *(const float4*)&sm[ot * 128 + mt * 16 + quad * 4];
            float4 bi4 = *(const float4*)&bm[ot * 128 + mt * 16 + quad * 4];
#pragma unroll
            for (int ntt = 0; ntt < 2; ++ntt) {
                int nrow = wav * 32 + ntt * 16 + l16;
                float v0 = fmaf(acc[mt][ntt][0], sc4.x, bi4.x) * qs;
                float v1 = fmaf(acc[mt][ntt][1], sc4.y, bi4.y) * qs;
                float v2 = fmaf(acc[mt][ntt][2], sc4.z, bi4.z) * qs;
                float v3 = fmaf(acc[mt][ntt][3], sc4.w, bi4.w) * qs;
                int cb = (mt * 2 + (quad >> 1)) ^ (nrow & 15);
                *(ushort4*)&sT[nrow * 128 + cb * 8 + (quad & 1) * 4] =
                    pack4bf(v0 > 0.f ? v0 : 0.f, v1 > 0.f ? v1 : 0.f,
                            v2 > 0.f ? v2 : 0.f, v3 > 0.f ? v3 : 0.f);
            }
        }
        __syncthreads();
        ushort* out = (mat == 0) ? qT : kT;
#pragma unroll
        for (int p = 0; p < 8; ++p) {
            int idx = p * 256 + tid;
            int row = idx >> 4, blk = idx & 15;   // row = n_local
            int4 d = *(const int4*)&sT[row * 128 + ((blk ^ (row & 15)) * 8)];
            *(int4*)&out[((size_t)b * kN + nt * 128 + row) * kC + ot * 128 + blk * 8] = d;
        }
    } else {
#pragma unroll
        for (int ntt = 0; ntt < 2; ++ntt) {
            int orow = wav * 32 + ntt * 16 + l16;
            float sc = sm[ot * 128 + orow], bi = bm[ot * 128 + orow];
#pragma unroll
            for (int mt = 0; mt < 8; ++mt) {
                float v0 = fmaf(acc[mt][ntt][0], sc, bi);
                float v1 = fmaf(acc[mt][ntt][1], sc, bi);
                float v2 = fmaf(acc[mt][ntt][2], sc, bi);
                float v3 = fmaf(acc[mt][ntt][3], sc, bi);
                int cb = (mt * 2 + (quad >> 1)) ^ (orow & 15);
                *(ushort4*)&sT[orow * 128 + cb * 8 + (quad & 1) * 4] =
                    pack4bf(v0 > 0.f ? v0 : 0.f, v1 > 0.f ? v1 : 0.f,
                            v2 > 0.f ? v2 : 0.f, v3 > 0.f ? v3 : 0.f);
            }
        }
        __syncthreads();
#pragma unroll
        for (int p = 0; p < 8; ++p) {
            int idx = p * 256 + tid;
            int row = idx >> 4, blk = idx & 15;   // row = o_local
            int4 d = *(const int4*)&sT[row * 128 + ((blk ^ (row & 15)) * 8)];
            *(int4*)&vB[((size_t)b * kC + ot * 128 + row) * kN + nt * 128 + blk * 8] = d;
        }
    }
}

// ---------------- MFMA flash attention: kSplit=1, Q-tile 256, 8 waves ------
// R26: kSplit 2 -> 1. attn is plateaued at 51-53us across geometry/
// occupancy/barrier variants (R4-R9); the win is DOWNSTREAM: Opart becomes
// a single normalized 7.3MB buffer, Ls + proj's entire split-combine VALU
// path disappear. Grid 224 (= 8 nt x 7 h x 4 b), NIT 32, R6's proven
// 2-buffer 1-barrier structure. Per-iter shfl quad-reduce deferred to
// epilogue (li accumulates per-lane partials; 2 shfls once, not 4 LDS-pipe
// ops x 32 iters). XCD map for 224 = 8 x 28: per-XCD set = one b's K+V
// (2MB <= 4MB L2).
__global__ __launch_bounds__(512, 2) void attn_kernel(
    const ushort* __restrict__ qT, const ushort* __restrict__ kT,
    const ushort* __restrict__ vB,
    ushort* __restrict__ Opart)
{
    const int j   = blockIdx.x;         // 0..223
    const int lid = (j & 7) * 28 + (j >> 3);
    const int b   = lid / 56;
    const int r2  = lid % 56;
    const int h   = r2 % 7;
    const int nt  = r2 / 7;             // 0..7
    const int n0  = nt * 256;

    const int tid = threadIdx.x;
    const int lane = tid & 63, wav = tid >> 6;    // 8 waves
    const int quad = lane >> 4, l16 = lane & 15;

    __shared__ __align__(16) ushort sKV[2][8192];   // 2 x 16 KB (K + V), 32 KB

    const ushort* qTb = qT + (size_t)b * kN * kC;
    const ushort* kTb = kT + (size_t)b * kN * kC;
    const ushort* vbb = vB + ((size_t)b * kC + h * 32) * kN;

    const int arr   = wav >> 2;          // 0 = K (wav 0-3), 1 = V (wav 4-7)
    const int rbase = (wav & 3) * 16;    // 16 rows per wave

    bf16x8 qf[2][2];
#pragma unroll
    for (int kk = 0; kk < 2; ++kk)
#pragma unroll
        for (int nt2 = 0; nt2 < 2; ++nt2) {
            int ng = n0 + wav * 32 + nt2 * 16 + l16;
            qf[kk][nt2] = *(const bf16x8*)(qTb + (size_t)ng * kC + h * 32 + kk * 32 + quad * 8);
        }

    f32x4 oacc[4][2];
#pragma unroll
    for (int wt = 0; wt < 4; ++wt)
#pragma unroll
        for (int nt2 = 0; nt2 < 2; ++nt2)
#pragma unroll
            for (int r = 0; r < 4; ++r) oacc[wt][nt2][r] = 0.f;
    float li[2] = {0.f, 0.f};   // per-lane partial; quad-aggregated at epilogue

    const int NIT = kN / 64;    // 32

    const int sa   = lane >> 3;           // dest sub-row within 8-row chunk
    const int sblk = (lane & 7) ^ sa;     // source block (swizzle on source)
    auto dmaTile = [&](int m0, int buf) {
#pragma unroll
        for (int p = 0; p < 2; ++p) {
            int rl = rbase + p * 8 + sa;
            const ushort* src = (arr == 0)
                ? (kTb + (size_t)(m0 + rl) * kC + h * 32 + sblk * 8)
                : (vbb + (size_t)rl * kN + m0 + sblk * 8);
            g2l16(src, &sKV[buf][arr * 4096 + (rbase + p * 8) * 64]);
        }
    };

    dmaTile(0, 0);
    __syncthreads();

    for (int it = 0; it < NIT; ++it) {
        const int cur = it & 1;
        const bool more = (it + 1 < NIT);
        if (more) dmaTile((it + 1) * 64, cur ^ 1);

        const ushort* sK = &sKV[cur][0];
        const ushort* sV = &sKV[cur][4096];

        // S^T[m][n] = sum_w K[w][m] Q[w][n]  (Q pre-scaled by log2e)
        f32x4 sacc[4][2];
#pragma unroll
        for (int mt = 0; mt < 4; ++mt)
#pragma unroll
            for (int nt2 = 0; nt2 < 2; ++nt2)
#pragma unroll
                for (int r = 0; r < 4; ++r) sacc[mt][nt2][r] = 0.f;
        __builtin_amdgcn_s_setprio(1);
#pragma unroll
        for (int kk = 0; kk < 2; ++kk)
#pragma unroll
            for (int mt = 0; mt < 4; ++mt) {
                int row = mt * 16 + l16;
                bf16x8 af = *(const bf16x8*)&sK[row * 64 + (((kk * 4 + quad) ^ (row & 7)) * 8)];
#pragma unroll
                for (int nt2 = 0; nt2 < 2; ++nt2)
                    sacc[mt][nt2] = __builtin_amdgcn_mfma_f32_16x16x32_bf16(
                        af, qf[kk][nt2], sacc[mt][nt2], 0, 0, 0);
            }
        __builtin_amdgcn_s_setprio(0);

        // softmax numerators: p = exp2(S') directly; keep packed P in regs.
        unsigned d[2][4][2];
#pragma unroll
        for (int nt2 = 0; nt2 < 2; ++nt2) {
            float sum = 0.f;
#pragma unroll
            for (int mt = 0; mt < 4; ++mt) {
                float p0 = fexp2(sacc[mt][nt2][0]);
                float p1 = fexp2(sacc[mt][nt2][1]);
                float p2 = fexp2(sacc[mt][nt2][2]);
                float p3 = fexp2(sacc[mt][nt2][3]);
                sum += (p0 + p1) + (p2 + p3);
                d[nt2][mt][0] = pk_bf16(p0, p1);
                d[nt2][mt][1] = pk_bf16(p2, p3);
            }
            li[nt2] += sum;   // per-lane partial (this lane's m-slice)
        }

        // O[w][n] += sum_m V[w][m] P[m][n]; C->B regroup via permlane cascade
#pragma unroll
        for (int ks = 0; ks < 2; ++ks) {
            bf16x8 pf[2];
#pragma unroll
            for (int nt2 = 0; nt2 < 2; ++nt2) {
                union { unsigned w[4]; bf16x8 v8; } pu;
#if __has_builtin(__builtin_amdgcn_permlane32_swap) && __has_builtin(__builtin_amdgcn_permlane16_swap)
#pragma unroll
                for (int rd = 0; rd < 2; ++rd) {
                    unsigned a = d[nt2][2 * ks][rd], bb = d[nt2][2 * ks + 1][rd];
                    auto r32 = __builtin_amdgcn_permlane32_swap(a, bb, false, false);
                    auto r16 = __builtin_amdgcn_permlane16_swap(r32[0], r32[1], false, false);
                    pu.w[rd]     = r16[0];
                    pu.w[2 + rd] = r16[1];
                }
#else
                const int gx = ((lane & 16) << 1) + l16;
                const int gy = gx + 16;
                const bool lo = (lane < 32);
#pragma unroll
                for (int rd = 0; rd < 2; ++rd) {
                    unsigned u = d[nt2][2 * ks][rd], v = d[nt2][2 * ks + 1][rd];
                    unsigned xu = (unsigned)__shfl((int)u, gx);
                    unsigned xv = (unsigned)__shfl((int)v, gx);
                    unsigned yu = (unsigned)__shfl((int)u, gy);
                    unsigned yv = (unsigned)__shfl((int)v, gy);
                    pu.w[rd]     = lo ? xu : xv;
                    pu.w[2 + rd] = lo ? yu : yv;
                }
#endif
                pf[nt2] = pu.v8;
            }
            __builtin_amdgcn_s_setprio(1);
#pragma unroll
            for (int wt = 0; wt < 4; ++wt) {
                int wr = wt * 16 + l16;
                bf16x8 vf = *(const bf16x8*)&sV[wr * 64 + (((ks * 4 + quad) ^ (wr & 7)) * 8)];
#pragma unroll
                for (int nt2 = 0; nt2 < 2; ++nt2)
                    oacc[wt][nt2] = __builtin_amdgcn_mfma_f32_16x16x32_bf16(
                        vf, pf[nt2], oacc[wt][nt2], 0, 0, 0);
            }
            __builtin_amdgcn_s_setprio(0);
        }

        __syncthreads();   // drains DMA (vmcnt) + K/V LDS ops (lgkm)
    }

    // ---- epilogue: finish row-sums, normalize, LDS-transpose O, store -----
#pragma unroll
    for (int nt2 = 0; nt2 < 2; ++nt2) {
        li[nt2] += __shfl_xor(li[nt2], 16);
        li[nt2] += __shfl_xor(li[nt2], 32);
    }
    ushort* sT = &sKV[0][0];    // 256 rows x 64 ch x 2B = 32 KB (spans both bufs)
#pragma unroll
    for (int wt = 0; wt < 4; ++wt)
#pragma unroll
        for (int nt2 = 0; nt2 < 2; ++nt2) {
            float inv = 1.f / li[nt2];
            int nrow = wav * 32 + nt2 * 16 + l16;   // 0..255
            int cb = (wt * 2 + (quad >> 1)) ^ (nrow & 7);
            *(ushort4*)&sT[nrow * 64 + cb * 8 + (quad & 1) * 4] =
                pack4bf(oacc[wt][nt2][0] * inv, oacc[wt][nt2][1] * inv,
                        oacc[wt][nt2][2] * inv, oacc[wt][nt2][3] * inv);
        }
    __syncthreads();
    int rsub = tid >> 3, blk = tid & 7;   // rsub 0..63
#pragma unroll
    for (int p = 0; p < 4; ++p) {
        int row = p * 64 + rsub;   // n_local 0..255
        int4 dd = *(const int4*)&sT[row * 64 + ((blk ^ (row & 7)) * 8)];
        *(int4*)&Opart[((size_t)b * kN + n0 + row) * kOC + h * 64 + blk * 8] = dd;
    }
}

// ---------------- final projection: pure DMA-GEMM (kSplit=1) ---------------
// R26: Opart is a single normalized bf16 buffer, so proj's split-combine
// staging (2x Opart reads, bf2f/fma/pack, rcp-divide recomputed 8x/row)
// is deleted. Tiles of Wf and Opart stage via global_load_lds with the
// qkv-proven swizzled-source pattern; inner loop = MFMA only.
__global__ __launch_bounds__(256, 4) void proj_kernel(
    const ushort* __restrict__ Opart, const ushort* __restrict__ Wfb,
    const float* __restrict__ bf_, const float* __restrict__ sf,
    const float* __restrict__ bff, float* __restrict__ out)
{
    const int nt = blockIdx.x;   // 32 tiles of 64 n
    const int ot = blockIdx.y;   // 4 tiles of 64 o
    const int b  = blockIdx.z;
    __shared__ __align__(16) ushort sA[2][64 * 64];   // Wf tile   (16 KB)
    __shared__ __align__(16) ushort sB[2][64 * 64];   // Opart tile (16 KB)
    const int tid = threadIdx.x;
    const int lane = tid & 63, wav = tid >> 6;   // 4 waves
    const int quad = lane >> 4, l16 = lane & 15;

    const ushort* Wt = Wfb + (size_t)(ot * 64) * kOC;
    const ushort* Ob = Opart + ((size_t)b * kN + nt * 64) * kOC;

    f32x4 acc[4];
#pragma unroll
    for (int ntt = 0; ntt < 4; ++ntt)
#pragma unroll
        for (int r = 0; r < 4; ++r) acc[ntt][r] = 0.f;

    const int sa   = lane >> 3;           // dest sub-row within 8-row chunk
    const int sblk = (lane & 7) ^ sa;     // source block (swizzle on source)
    auto dmaT = [&](int kt, int buf) {
        int k0 = kt * 64;
#pragma unroll
        for (int p = 0; p < 2; ++p) {
            int row = wav * 16 + p * 8 + sa;
            int dbase = (wav * 16 + p * 8) * 64;
            g2l16(Wt + (size_t)row * kOC + k0 + sblk * 8, &sA[buf][dbase]);
            g2l16(Ob + (size_t)row * kOC + k0 + sblk * 8, &sB[buf][dbase]);
        }
    };

    dmaT(0, 0);
    __syncthreads();

    for (int kt = 0; kt < 7; ++kt) {
        const int cur = kt & 1;
        const bool more = (kt < 6);
        if (more) dmaT(kt + 1, cur ^ 1);
#pragma unroll
        for (int ks = 0; ks < 2; ++ks) {
            int arow = wav * 16 + l16;
            bf16x8 af = *(const bf16x8*)&sA[cur][arow * 64 + (((ks * 4 + quad) ^ (arow & 7)) * 8)];
#pragma unroll
            for (int ntt = 0; ntt < 4; ++ntt) {
                int brow = ntt * 16 + l16;
                bf16x8 bfr = *(const bf16x8*)&sB[cur][brow * 64 + (((ks * 4 + quad) ^ (brow & 7)) * 8)];
                acc[ntt] = __builtin_amdgcn_mfma_f32_16x16x32_bf16(af, bfr, acc[ntt], 0, 0, 0);
            }
        }
        __syncthreads();
    }
#pragma unroll
    for (int r = 0; r < 4; ++r) {
        int o = ot * 64 + wav * 16 + quad * 4 + r;
        float bfv = bf_[o], sfv = sf[o], bffv = bff[o];
#pragma unroll
        for (int ntt = 0; ntt < 4; ++ntt) {
            int n = nt * 64 + ntt * 16 + l16;
            float y = fmaf(acc[ntt][r] + bfv, sfv, bffv);
            out[((size_t)b * kC + o) * kN + n] = y > 0.f ? y : 0.f;
        }
    }
}

extern "C" void kernel_launch(void* const* d_in, const int* in_sizes, int n_in,
                              void* d_out, int out_size, void* d_ws, size_t ws_size,
                              hipStream_t stream) {
    const float* x   = (const float*)d_in[0];
    const float* Wq  = (const float*)d_in[1];
    const float* sq  = (const float*)d_in[2];
    const float* bq  = (const float*)d_in[3];
    const float* Wk  = (const float*)d_in[4];
    const float* sk  = (const float*)d_in[5];
    const float* bk  = (const float*)d_in[6];
    const float* Wv  = (const float*)d_in[7];
    const float* sv  = (const float*)d_in[8];
    const float* bv  = (const float*)d_in[9];
    const float* Wf  = (const float*)d_in[10];
    const float* bf_ = (const float*)d_in[11];
    const float* sf  = (const float*)d_in[12];
    const float* bff = (const float*)d_in[13];
    float* out = (float*)d_out;

    char* ws = (char*)d_ws;
    ushort* xT  = (ushort*)(ws);                         // 4,194,304
    ushort* Wqb = (ushort*)(ws + 4194304);               // 131,072
    ushort* Wkb = (ushort*)(ws + 4325376);               // 131,072
    ushort* Wvb = (ushort*)(ws + 4456448);               // 131,072
    ushort* Wfb = (ushort*)(ws + 4587520);               // 229,376
    ushort* qT  = (ushort*)(ws + 4816896);               // 4,194,304
    ushort* kT  = (ushort*)(ws + 9011200);               // 4,194,304
    ushort* vB  = (ushort*)(ws + 13205504);              // 4,194,304
    ushort* Opart = (ushort*)(ws + 17399808);            // 7,340,032 (single)

    prep_kernel<<<dim3(960), 256, 0, stream>>>(
        x, Wq, Wk, Wv, Wf, xT, Wqb, Wkb, Wvb, Wfb);
    qkv_kernel<<<dim3(kN / 128, kC / 128, kB * 3), 256, 0, stream>>>(
        xT, Wqb, Wkb, Wvb, sq, bq, sk, bk, sv, bv, qT, kT, vB);
    attn_kernel<<<dim3(224), 512, 0, stream>>>(
        qT, kT, vB, Opart);
    proj_kernel<<<dim3(kN / 64, kC / 64, kB), 256, 0, stream>>>(
        Opart, Wfb, bf_, sf, bff, out);
}

// Round 11
// 151.020 us; speedup vs baseline: 1.0143x; 1.0143x over previous
//
#include <hip/hip_runtime.h>
#include <hip/hip_bf16.h>

typedef __attribute__((ext_vector_type(8))) short bf16x8;
typedef __attribute__((ext_vector_type(4))) float f32x4;

namespace {
constexpr int kC = 256;
constexpr int kN = 2048;
constexpr int kB = 4;
constexpr int kHeads = 7;
constexpr int kOC = kHeads * 64;     // 448
constexpr float kLog2e = 1.44269504f;
}

static __device__ __forceinline__ float bf2f(ushort u) {
    union { unsigned u; float f; } v; v.u = ((unsigned)u) << 16;
    return v.f;
}
// packed f32x2 -> bf16x2 (RNE); lowers to v_cvt_pk_bf16_f32 when available
static __device__ __forceinline__ unsigned pk_bf16(float a, float b) {
    __hip_bfloat162 h = __float22bfloat162_rn(make_float2(a, b));
    union { __hip_bfloat162 h; unsigned u; } v; v.h = h;
    return v.u;
}
static __device__ __forceinline__ ushort4 pack4bf(float a, float b, float c, float d) {
    union { ushort4 s; uint2 u; } v;
    v.u.x = pk_bf16(a, b); v.u.y = pk_bf16(c, d);
    return v.s;
}
static __device__ __forceinline__ float fexp2(float x) {
#if __has_builtin(__builtin_amdgcn_exp2f)
    return __builtin_amdgcn_exp2f(x);
#else
    return exp2f(x);
#endif
}
// async global->LDS DMA, 16 B per lane. lds dest = l + lane*16 (wave-uniform l).
static __device__ __forceinline__ void g2l16(const ushort* g, ushort* l) {
    __builtin_amdgcn_global_load_lds(
        (const __attribute__((address_space(1))) void*)g,
        (__attribute__((address_space(3))) void*)l,
        16, 0, 0);
}

// ---------------- fused prep: weight cast + x transpose (one launch) -------
__global__ __launch_bounds__(256) void prep_kernel(
    const float* __restrict__ x,
    const float* __restrict__ Wq, const float* __restrict__ Wk,
    const float* __restrict__ Wv, const float* __restrict__ Wf,
    ushort* __restrict__ xT,
    ushort* __restrict__ wq, ushort* __restrict__ wk,
    ushort* __restrict__ wv, ushort* __restrict__ wf)
{
    __shared__ float T[64][65];
    const int bid = blockIdx.x;
    const int tid = threadIdx.x;
    if (bid < 512) {
        // ---- transpose+cast: x[b][c][n] fp32 -> xT[b][n][c] bf16 ----
        const int nt = bid & 31, ct = (bid >> 5) & 3, b = bid >> 7;
        const float* xb = x + ((size_t)b * kC + ct * 64) * kN + nt * 64;
#pragma unroll
        for (int p = 0; p < 16; ++p) {
            int idx = p * 256 + tid;
            int cc = idx >> 6, nn = idx & 63;
            T[cc][nn] = xb[(size_t)cc * kN + nn];
        }
        __syncthreads();
        ushort* xTb = xT + ((size_t)b * kN + nt * 64) * kC + ct * 64;
#pragma unroll
        for (int p = 0; p < 4; ++p) {
            int nn = p * 16 + (tid >> 4);
            int c4 = (tid & 15) * 4;
            *(ushort4*)&xTb[(size_t)nn * kC + c4] =
                pack4bf(T[c4 + 0][nn], T[c4 + 1][nn], T[c4 + 2][nn], T[c4 + 3][nn]);
        }
    } else {
        // ---- weight cast fp32 -> bf16 ----
        const int j = bid - 512;            // 0..447
        const int which = j / 112, bx = j % 112;
        const float* src = which == 0 ? Wq : which == 1 ? Wk : which == 2 ? Wv : Wf;
        ushort* dst      = which == 0 ? wq : which == 1 ? wk : which == 2 ? wv : wf;
        int n = (which == 3) ? kC * kOC : kC * kC;
        int i = (bx * 256 + tid) * 4;
        if (i < n) {
            float4 v = *(const float4*)(src + i);
            *(ushort4*)(dst + i) = pack4bf(v.x, v.y, v.z, v.w);
        }
    }
}

// ---------------- QKV projection: 128x128 tile, 512 threads (8 waves) ------
// R27: 256 -> 512 threads. Old config: 64KB LDS capped at 2 blocks/CU x 4
// waves = 2 waves/SIMD — the worst occupancy in the pipeline, on a
// barrier-drain loop (4 kt x 32KB DMA each, full vmcnt drain per kt). 8
// waves at (512,2) = 4 waves/SIMD: per-wave MFMA work halves (2 o-half x
// 4 n-quarter decomposition), per-thread DMA halves, drains hide behind 2x
// resident waves. + bijective XCD swizzle (384 = 8x48) grouping same-b
// blocks for xT L2 reuse. Math/layout identical to the proven 256-thr
// version (same swizzles, same epilogues at 512-thr indexing).
__global__ __launch_bounds__(512, 2) void qkv_kernel(
    const ushort* __restrict__ xT,
    const ushort* __restrict__ Wqb, const ushort* __restrict__ Wkb, const ushort* __restrict__ Wvb,
    const float* __restrict__ sq, const float* __restrict__ bq,
    const float* __restrict__ sk, const float* __restrict__ bk,
    const float* __restrict__ sv, const float* __restrict__ bv,
    ushort* __restrict__ qT, ushort* __restrict__ kT, ushort* __restrict__ vB)
{
    const int j   = blockIdx.x;              // 0..383
    const int lid = (j & 7) * 48 + (j >> 3); // XCD-grouped
    const int nt  = lid & 15;
    const int ot  = (lid >> 4) & 1;
    const int zz  = lid >> 5;                // 0..11
    const int b   = zz / 3;
    const int mat = zz % 3;
    const ushort* Wb = mat == 0 ? Wqb : mat == 1 ? Wkb : Wvb;
    const float* sm = mat == 0 ? sq : mat == 1 ? sk : sv;
    const float* bm = mat == 0 ? bq : mat == 1 ? bk : bv;

    __shared__ __align__(16) ushort lds[4][128 * 64];   // 64 KB

    const int tid = threadIdx.x;
    const int lane = tid & 63, wav = tid >> 6;   // 8 waves
    const int quad = lane >> 4, l16 = lane & 15;
    const int oh = wav >> 2;     // 0/1: rowB 64-row half
    const int nq = wav & 3;      // 0..3: colB 32-row quarter

    const ushort* xTb = xT + ((size_t)b * kN + nt * 128) * kC;
    const ushort* Wt  = Wb + (size_t)(ot * 128) * kC;

    f32x4 acc[4][2];
#pragma unroll
    for (int mt = 0; mt < 4; ++mt)
#pragma unroll
        for (int ntt = 0; ntt < 2; ++ntt)
#pragma unroll
            for (int r = 0; r < 4; ++r) acc[mt][ntt][r] = 0.f;

    const int sa   = lane >> 3;           // dest sub-row within 8-row chunk
    const int sblk = (lane & 7) ^ sa;     // source block (swizzle on source)
    auto dmaK = [&](int k0, int buf) {
#pragma unroll
        for (int p = 0; p < 2; ++p) {
            int row = wav * 16 + p * 8 + sa;
            size_t so = (size_t)row * kC + k0 + sblk * 8;
            int dbase = (wav * 16 + p * 8) * 64;
            g2l16(Wt + so,  &lds[buf][dbase]);
            g2l16(xTb + so, &lds[2 + buf][dbase]);
        }
    };

    dmaK(0, 0);
    __syncthreads();

    for (int kt = 0; kt < 4; ++kt) {
        const int cur = kt & 1;
        const bool more = (kt < 3);
        if (more) dmaK((kt + 1) * 64, cur ^ 1);

        const ushort* rowB = (mat < 2) ? lds[cur] : lds[2 + cur];
        const ushort* colB = (mat < 2) ? lds[2 + cur] : lds[cur];
#pragma unroll
        for (int ks = 0; ks < 2; ++ks) {
            bf16x8 bfr[2];
#pragma unroll
            for (int ntt = 0; ntt < 2; ++ntt) {
                int row = nq * 32 + ntt * 16 + l16;
                bfr[ntt] = *(const bf16x8*)&colB[row * 64 + (((ks * 4 + quad) ^ (row & 7)) * 8)];
            }
#pragma unroll
            for (int mt = 0; mt < 4; ++mt) {
                int row = oh * 64 + mt * 16 + l16;
                bf16x8 af = *(const bf16x8*)&rowB[row * 64 + (((ks * 4 + quad) ^ (row & 7)) * 8)];
#pragma unroll
                for (int ntt = 0; ntt < 2; ++ntt)
                    acc[mt][ntt] = __builtin_amdgcn_mfma_f32_16x16x32_bf16(
                        af, bfr[ntt], acc[mt][ntt], 0, 0, 0);
            }
        }
        __syncthreads();
    }

    // epilogue: 128x128 transpose gather in lds[0..1] (32 KB, contiguous)
    ushort* sT = &lds[0][0];
    const float qs = (mat == 0) ? kLog2e : 1.f;   // bake log2e into q

    if (mat < 2) {
        // C: o = oh*64 + mt*16 + quad*4 + r (rowB = W), n = nq*32 + ntt*16 + l16
#pragma unroll
        for (int mt = 0; mt < 4; ++mt) {
            float4 sc4 = *(const float4*)&sm[ot * 128 + oh * 64 + mt * 16 + quad * 4];
            float4 bi4 = *(const float4*)&bm[ot * 128 + oh * 64 + mt * 16 + quad * 4];
#pragma unroll
            for (int ntt = 0; ntt < 2; ++ntt) {
                int nrow = nq * 32 + ntt * 16 + l16;
                float v0 = fmaf(acc[mt][ntt][0], sc4.x, bi4.x) * qs;
                float v1 = fmaf(acc[mt][ntt][1], sc4.y, bi4.y) * qs;
                float v2 = fmaf(acc[mt][ntt][2], sc4.z, bi4.z) * qs;
                float v3 = fmaf(acc[mt][ntt][3], sc4.w, bi4.w) * qs;
                int cb = (oh * 8 + mt * 2 + (quad >> 1)) ^ (nrow & 15);
                *(ushort4*)&sT[nrow * 128 + cb * 8 + (quad & 1) * 4] =
                    pack4bf(v0 > 0.f ? v0 : 0.f, v1 > 0.f ? v1 : 0.f,
                            v2 > 0.f ? v2 : 0.f, v3 > 0.f ? v3 : 0.f);
            }
        }
        __syncthreads();
        ushort* out = (mat == 0) ? qT : kT;
#pragma unroll
        for (int p = 0; p < 4; ++p) {
            int idx = p * 512 + tid;
            int row = idx >> 4, blk = idx & 15;   // row = n_local
            int4 d = *(const int4*)&sT[row * 128 + ((blk ^ (row & 15)) * 8)];
            *(int4*)&out[((size_t)b * kN + nt * 128 + row) * kC + ot * 128 + blk * 8] = d;
        }
    } else {
        // rowB = xT: C: n = oh*64 + mt*16 + quad*4 + r, o = nq*32 + ntt*16 + l16
#pragma unroll
        for (int ntt = 0; ntt < 2; ++ntt) {
            int orow = nq * 32 + ntt * 16 + l16;
            float sc = sm[ot * 128 + orow], bi = bm[ot * 128 + orow];
#pragma unroll
            for (int mt = 0; mt < 4; ++mt) {
                float v0 = fmaf(acc[mt][ntt][0], sc, bi);
                float v1 = fmaf(acc[mt][ntt][1], sc, bi);
                float v2 = fmaf(acc[mt][ntt][2], sc, bi);
                float v3 = fmaf(acc[mt][ntt][3], sc, bi);
                int cb = (oh * 8 + mt * 2 + (quad >> 1)) ^ (orow & 15);
                *(ushort4*)&sT[orow * 128 + cb * 8 + (quad & 1) * 4] =
                    pack4bf(v0 > 0.f ? v0 : 0.f, v1 > 0.f ? v1 : 0.f,
                            v2 > 0.f ? v2 : 0.f, v3 > 0.f ? v3 : 0.f);
            }
        }
        __syncthreads();
#pragma unroll
        for (int p = 0; p < 4; ++p) {
            int idx = p * 512 + tid;
            int row = idx >> 4, blk = idx & 15;   // row = o_local
            int4 d = *(const int4*)&sT[row * 128 + ((blk ^ (row & 15)) * 8)];
            *(int4*)&vB[((size_t)b * kC + ot * 128 + row) * kN + nt * 128 + blk * 8] = d;
        }
    }
}

// ---------------- MFMA flash attention: kSplit=1, Q-tile 256, 8 waves ------
// R26 (kept): single normalized Opart, no Ls. Grid 224 (8 nt x 7 h x 4 b),
// NIT 32, R6's 2-buffer 1-barrier structure, permlane P-regroup, deferred
// quad-reduce. XCD map 224 = 8 x 28.
__global__ __launch_bounds__(512, 2) void attn_kernel(
    const ushort* __restrict__ qT, const ushort* __restrict__ kT,
    const ushort* __restrict__ vB,
    ushort* __restrict__ Opart)
{
    const int j   = blockIdx.x;         // 0..223
    const int lid = (j & 7) * 28 + (j >> 3);
    const int b   = lid / 56;
    const int r2  = lid % 56;
    const int h   = r2 % 7;
    const int nt  = r2 / 7;             // 0..7
    const int n0  = nt * 256;

    const int tid = threadIdx.x;
    const int lane = tid & 63, wav = tid >> 6;    // 8 waves
    const int quad = lane >> 4, l16 = lane & 15;

    __shared__ __align__(16) ushort sKV[2][8192];   // 2 x 16 KB (K + V), 32 KB

    const ushort* qTb = qT + (size_t)b * kN * kC;
    const ushort* kTb = kT + (size_t)b * kN * kC;
    const ushort* vbb = vB + ((size_t)b * kC + h * 32) * kN;

    const int arr   = wav >> 2;          // 0 = K (wav 0-3), 1 = V (wav 4-7)
    const int rbase = (wav & 3) * 16;    // 16 rows per wave

    bf16x8 qf[2][2];
#pragma unroll
    for (int kk = 0; kk < 2; ++kk)
#pragma unroll
        for (int nt2 = 0; nt2 < 2; ++nt2) {
            int ng = n0 + wav * 32 + nt2 * 16 + l16;
            qf[kk][nt2] = *(const bf16x8*)(qTb + (size_t)ng * kC + h * 32 + kk * 32 + quad * 8);
        }

    f32x4 oacc[4][2];
#pragma unroll
    for (int wt = 0; wt < 4; ++wt)
#pragma unroll
        for (int nt2 = 0; nt2 < 2; ++nt2)
#pragma unroll
            for (int r = 0; r < 4; ++r) oacc[wt][nt2][r] = 0.f;
    float li[2] = {0.f, 0.f};   // per-lane partial; quad-aggregated at epilogue

    const int NIT = kN / 64;    // 32

    const int sa   = lane >> 3;           // dest sub-row within 8-row chunk
    const int sblk = (lane & 7) ^ sa;     // source block (swizzle on source)
    auto dmaTile = [&](int m0, int buf) {
#pragma unroll
        for (int p = 0; p < 2; ++p) {
            int rl = rbase + p * 8 + sa;
            const ushort* src = (arr == 0)
                ? (kTb + (size_t)(m0 + rl) * kC + h * 32 + sblk * 8)
                : (vbb + (size_t)rl * kN + m0 + sblk * 8);
            g2l16(src, &sKV[buf][arr * 4096 + (rbase + p * 8) * 64]);
        }
    };

    dmaTile(0, 0);
    __syncthreads();

    for (int it = 0; it < NIT; ++it) {
        const int cur = it & 1;
        const bool more = (it + 1 < NIT);
        if (more) dmaTile((it + 1) * 64, cur ^ 1);

        const ushort* sK = &sKV[cur][0];
        const ushort* sV = &sKV[cur][4096];

        // S^T[m][n] = sum_w K[w][m] Q[w][n]  (Q pre-scaled by log2e)
        f32x4 sacc[4][2];
#pragma unroll
        for (int mt = 0; mt < 4; ++mt)
#pragma unroll
            for (int nt2 = 0; nt2 < 2; ++nt2)
#pragma unroll
                for (int r = 0; r < 4; ++r) sacc[mt][nt2][r] = 0.f;
        __builtin_amdgcn_s_setprio(1);
#pragma unroll
        for (int kk = 0; kk < 2; ++kk)
#pragma unroll
            for (int mt = 0; mt < 4; ++mt) {
                int row = mt * 16 + l16;
                bf16x8 af = *(const bf16x8*)&sK[row * 64 + (((kk * 4 + quad) ^ (row & 7)) * 8)];
#pragma unroll
                for (int nt2 = 0; nt2 < 2; ++nt2)
                    sacc[mt][nt2] = __builtin_amdgcn_mfma_f32_16x16x32_bf16(
                        af, qf[kk][nt2], sacc[mt][nt2], 0, 0, 0);
            }
        __builtin_amdgcn_s_setprio(0);

        // softmax numerators: p = exp2(S') directly; keep packed P in regs.
        unsigned d[2][4][2];
#pragma unroll
        for (int nt2 = 0; nt2 < 2; ++nt2) {
            float sum = 0.f;
#pragma unroll
            for (int mt = 0; mt < 4; ++mt) {
                float p0 = fexp2(sacc[mt][nt2][0]);
                float p1 = fexp2(sacc[mt][nt2][1]);
                float p2 = fexp2(sacc[mt][nt2][2]);
                float p3 = fexp2(sacc[mt][nt2][3]);
                sum += (p0 + p1) + (p2 + p3);
                d[nt2][mt][0] = pk_bf16(p0, p1);
                d[nt2][mt][1] = pk_bf16(p2, p3);
            }
            li[nt2] += sum;   // per-lane partial (this lane's m-slice)
        }

        // O[w][n] += sum_m V[w][m] P[m][n]; C->B regroup via permlane cascade
#pragma unroll
        for (int ks = 0; ks < 2; ++ks) {
            bf16x8 pf[2];
#pragma unroll
            for (int nt2 = 0; nt2 < 2; ++nt2) {
                union { unsigned w[4]; bf16x8 v8; } pu;
#if __has_builtin(__builtin_amdgcn_permlane32_swap) && __has_builtin(__builtin_amdgcn_permlane16_swap)
#pragma unroll
                for (int rd = 0; rd < 2; ++rd) {
                    unsigned a = d[nt2][2 * ks][rd], bb = d[nt2][2 * ks + 1][rd];
                    auto r32 = __builtin_amdgcn_permlane32_swap(a, bb, false, false);
                    auto r16 = __builtin_amdgcn_permlane16_swap(r32[0], r32[1], false, false);
                    pu.w[rd]     = r16[0];
                    pu.w[2 + rd] = r16[1];
                }
#else
                const int gx = ((lane & 16) << 1) + l16;
                const int gy = gx + 16;
                const bool lo = (lane < 32);
#pragma unroll
                for (int rd = 0; rd < 2; ++rd) {
                    unsigned u = d[nt2][2 * ks][rd], v = d[nt2][2 * ks + 1][rd];
                    unsigned xu = (unsigned)__shfl((int)u, gx);
                    unsigned xv = (unsigned)__shfl((int)v, gx);
                    unsigned yu = (unsigned)__shfl((int)u, gy);
                    unsigned yv = (unsigned)__shfl((int)v, gy);
                    pu.w[rd]     = lo ? xu : xv;
                    pu.w[2 + rd] = lo ? yu : yv;
                }
#endif
                pf[nt2] = pu.v8;
            }
            __builtin_amdgcn_s_setprio(1);
#pragma unroll
            for (int wt = 0; wt < 4; ++wt) {
                int wr = wt * 16 + l16;
                bf16x8 vf = *(const bf16x8*)&sV[wr * 64 + (((ks * 4 + quad) ^ (wr & 7)) * 8)];
#pragma unroll
                for (int nt2 = 0; nt2 < 2; ++nt2)
                    oacc[wt][nt2] = __builtin_amdgcn_mfma_f32_16x16x32_bf16(
                        vf, pf[nt2], oacc[wt][nt2], 0, 0, 0);
            }
            __builtin_amdgcn_s_setprio(0);
        }

        __syncthreads();   // drains DMA (vmcnt) + K/V LDS ops (lgkm)
    }

    // ---- epilogue: finish row-sums, normalize, LDS-transpose O, store -----
#pragma unroll
    for (int nt2 = 0; nt2 < 2; ++nt2) {
        li[nt2] += __shfl_xor(li[nt2], 16);
        li[nt2] += __shfl_xor(li[nt2], 32);
    }
    ushort* sT = &sKV[0][0];    // 256 rows x 64 ch x 2B = 32 KB (spans both bufs)
#pragma unroll
    for (int wt = 0; wt < 4; ++wt)
#pragma unroll
        for (int nt2 = 0; nt2 < 2; ++nt2) {
            float inv = 1.f / li[nt2];
            int nrow = wav * 32 + nt2 * 16 + l16;   // 0..255
            int cb = (wt * 2 + (quad >> 1)) ^ (nrow & 7);
            *(ushort4*)&sT[nrow * 64 + cb * 8 + (quad & 1) * 4] =
                pack4bf(oacc[wt][nt2][0] * inv, oacc[wt][nt2][1] * inv,
                        oacc[wt][nt2][2] * inv, oacc[wt][nt2][3] * inv);
        }
    __syncthreads();
    int rsub = tid >> 3, blk = tid & 7;   // rsub 0..63
#pragma unroll
    for (int p = 0; p < 4; ++p) {
        int row = p * 64 + rsub;   // n_local 0..255
        int4 dd = *(const int4*)&sT[row * 64 + ((blk ^ (row & 7)) * 8)];
        *(int4*)&Opart[((size_t)b * kN + n0 + row) * kOC + h * 64 + blk * 8] = dd;
    }
}

// ---------------- final projection: pure DMA-GEMM (kSplit=1) ---------------
__global__ __launch_bounds__(256, 4) void proj_kernel(
    const ushort* __restrict__ Opart, const ushort* __restrict__ Wfb,
    const float* __restrict__ bf_, const float* __restrict__ sf,
    const float* __restrict__ bff, float* __restrict__ out)
{
    const int nt = blockIdx.x;   // 32 tiles of 64 n
    const int ot = blockIdx.y;   // 4 tiles of 64 o
    const int b  = blockIdx.z;
    __shared__ __align__(16) ushort sA[2][64 * 64];   // Wf tile   (16 KB)
    __shared__ __align__(16) ushort sB[2][64 * 64];   // Opart tile (16 KB)
    const int tid = threadIdx.x;
    const int lane = tid & 63, wav = tid >> 6;   // 4 waves
    const int quad = lane >> 4, l16 = lane & 15;

    const ushort* Wt = Wfb + (size_t)(ot * 64) * kOC;
    const ushort* Ob = Opart + ((size_t)b * kN + nt * 64) * kOC;

    f32x4 acc[4];
#pragma unroll
    for (int ntt = 0; ntt < 4; ++ntt)
#pragma unroll
        for (int r = 0; r < 4; ++r) acc[ntt][r] = 0.f;

    const int sa   = lane >> 3;           // dest sub-row within 8-row chunk
    const int sblk = (lane & 7) ^ sa;     // source block (swizzle on source)
    auto dmaT = [&](int kt, int buf) {
        int k0 = kt * 64;
#pragma unroll
        for (int p = 0; p < 2; ++p) {
            int row = wav * 16 + p * 8 + sa;
            int dbase = (wav * 16 + p * 8) * 64;
            g2l16(Wt + (size_t)row * kOC + k0 + sblk * 8, &sA[buf][dbase]);
            g2l16(Ob + (size_t)row * kOC + k0 + sblk * 8, &sB[buf][dbase]);
        }
    };

    dmaT(0, 0);
    __syncthreads();

    for (int kt = 0; kt < 7; ++kt) {
        const int cur = kt & 1;
        const bool more = (kt < 6);
        if (more) dmaT(kt + 1, cur ^ 1);
#pragma unroll
        for (int ks = 0; ks < 2; ++ks) {
            int arow = wav * 16 + l16;
            bf16x8 af = *(const bf16x8*)&sA[cur][arow * 64 + (((ks * 4 + quad) ^ (arow & 7)) * 8)];
#pragma unroll
            for (int ntt = 0; ntt < 4; ++ntt) {
                int brow = ntt * 16 + l16;
                bf16x8 bfr = *(const bf16x8*)&sB[cur][brow * 64 + (((ks * 4 + quad) ^ (brow & 7)) * 8)];
                acc[ntt] = __builtin_amdgcn_mfma_f32_16x16x32_bf16(af, bfr, acc[ntt], 0, 0, 0);
            }
        }
        __syncthreads();
    }
#pragma unroll
    for (int r = 0; r < 4; ++r) {
        int o = ot * 64 + wav * 16 + quad * 4 + r;
        float bfv = bf_[o], sfv = sf[o], bffv = bff[o];
#pragma unroll
        for (int ntt = 0; ntt < 4; ++ntt) {
            int n = nt * 64 + ntt * 16 + l16;
            float y = fmaf(acc[ntt][r] + bfv, sfv, bffv);
            out[((size_t)b * kC + o) * kN + n] = y > 0.f ? y : 0.f;
        }
    }
}

extern "C" void kernel_launch(void* const* d_in, const int* in_sizes, int n_in,
                              void* d_out, int out_size, void* d_ws, size_t ws_size,
                              hipStream_t stream) {
    const float* x   = (const float*)d_in[0];
    const float* Wq  = (const float*)d_in[1];
    const float* sq  = (const float*)d_in[2];
    const float* bq  = (const float*)d_in[3];
    const float* Wk  = (const float*)d_in[4];
    const float* sk  = (const float*)d_in[5];
    const float* bk  = (const float*)d_in[6];
    const float* Wv  = (const float*)d_in[7];
    const float* sv  = (const float*)d_in[8];
    const float* bv  = (const float*)d_in[9];
    const float* Wf  = (const float*)d_in[10];
    const float* bf_ = (const float*)d_in[11];
    const float* sf  = (const float*)d_in[12];
    const float* bff = (const float*)d_in[13];
    float* out = (float*)d_out;

    char* ws = (char*)d_ws;
    ushort* xT  = (ushort*)(ws);                         // 4,194,304
    ushort* Wqb = (ushort*)(ws + 4194304);               // 131,072
    ushort* Wkb = (ushort*)(ws + 4325376);               // 131,072
    ushort* Wvb = (ushort*)(ws + 4456448);               // 131,072
    ushort* Wfb = (ushort*)(ws + 4587520);               // 229,376
    ushort* qT  = (ushort*)(ws + 4816896);               // 4,194,304
    ushort* kT  = (ushort*)(ws + 9011200);               // 4,194,304
    ushort* vB  = (ushort*)(ws + 13205504);              // 4,194,304
    ushort* Opart = (ushort*)(ws + 17399808);            // 7,340,032 (single)

    prep_kernel<<<dim3(960), 256, 0, stream>>>(
        x, Wq, Wk, Wv, Wf, xT, Wqb, Wkb, Wvb, Wfb);
    qkv_kernel<<<dim3(384), 512, 0, stream>>>(
        xT, Wqb, Wkb, Wvb, sq, bq, sk, bk, sv, bv, qT, kT, vB);
    attn_kernel<<<dim3(224), 512, 0, stream>>>(
        qT, kT, vB, Opart);
    proj_kernel<<<dim3(kN / 64, kC / 64, kB), 256, 0, stream>>>(
        Opart, Wfb, bf_, sf, bff, out);
}